// Round 12
// baseline (33.406 us; speedup 1.0000x reference)
//
#include <hip/hip_runtime.h>

#define BD 4
#define CD 3
#define HD 512
#define WD 512
#define NPAT 4096
#define NP (BD * NPAT)            // 16384 patches
#define PLANE (HD * WD)
#define NBLK 512                  // persistent-ish: 2 blocks/CU, 8 waves/CU
#define ITER 4                    // chunks per wave (2 patches each)
#define TOTAL_ELEMS (4.0 * 3.0 * 4096.0 * 256.0)   // 12,582,912
#define CSTRIDE 260               // u8 count-row stride

typedef float f4 __attribute__((ext_vector_type(4), aligned(4)));

// ---- DPP-based cross-lane add: VALU pipe, not DS ----
template <int CTRL>
__device__ __forceinline__ float dpp_add(float x) {
    int y = __builtin_amdgcn_update_dpp(0, __float_as_int(x), CTRL, 0xF, 0xF, true);
    return x + __int_as_float(y);
}

// 64-lane sum: 4 DPP steps (within row of 16) + 2 DS shuffles (xor16, xor32).
__device__ __forceinline__ float wave_sum64(float x) {
    x = dpp_add<0xB1>(x);    // quad_perm xor1
    x = dpp_add<0x4E>(x);    // quad_perm xor2
    x = dpp_add<0x124>(x);   // row_ror:4
    x = dpp_add<0x128>(x);   // row_ror:8
    x += __shfl_xor(x, 16, 64);
    x += __shfl_xor(x, 32, 64);
    return x;
}

// ---- kernel 1: per-batch 256-key counting sort by (h>>5, w>>5) ----
__global__ __launch_bounds__(256) void build_order(
    const int* __restrict__ coords, unsigned int* __restrict__ order)
{
    __shared__ unsigned char  cnt[256 * CSTRIDE];
    __shared__ unsigned short total[256];
    __shared__ unsigned int   base[256];

    const int t = threadIdx.x;
    const int b = blockIdx.x;

    {
        unsigned int* row = (unsigned int*)(cnt + t * CSTRIDE);
        #pragma unroll
        for (int k = 0; k < CSTRIDE / 4; ++k) row[k] = 0u;
    }
    __syncthreads();

    const int2* c2 = (const int2*)coords;
    unsigned int  pk[16];
    unsigned char kk[16];
    #pragma unroll
    for (int i = 0; i < 16; ++i) {
        const int p = (b << 12) + (i << 8) + t;
        const int2 hw = c2[p];
        pk[i] = ((unsigned)b << 18) | ((unsigned)hw.x << 9) | (unsigned)hw.y;
        kk[i] = (unsigned char)(((hw.x >> 5) << 4) | (hw.y >> 5));
        cnt[t * CSTRIDE + kk[i]]++;
    }
    __syncthreads();

    {
        unsigned int run = 0;
        for (int tt = 0; tt < 256; ++tt) {
            const unsigned int v = cnt[tt * CSTRIDE + t];
            cnt[tt * CSTRIDE + t] = (unsigned char)run;
            run += v;
        }
        total[t] = (unsigned short)run;
    }
    __syncthreads();

    if (t < 64) {
        const unsigned int t0 = total[4 * t],     t1 = total[4 * t + 1];
        const unsigned int t2 = total[4 * t + 2], t3 = total[4 * t + 3];
        const unsigned int lsum = t0 + t1 + t2 + t3;
        unsigned int x = lsum;
        #pragma unroll
        for (int d = 1; d < 64; d <<= 1) {
            const unsigned int v = __shfl_up(x, d, 64);
            if (t >= d) x += v;
        }
        const unsigned int excl = x - lsum;
        base[4 * t]     = excl;
        base[4 * t + 1] = excl + t0;
        base[4 * t + 2] = excl + t0 + t1;
        base[4 * t + 3] = excl + t0 + t1 + t2;
    }
    __syncthreads();

    #pragma unroll
    for (int i = 0; i < 16; ++i) {
        const int key = kk[i];
        const unsigned int pos = base[key] + cnt[t * CSTRIDE + key];
        cnt[t * CSTRIDE + key]++;
        order[(b << 12) + pos] = pk[i];
    }
}

// ---- kernel 2: persistent-ish, 4 sequential chunks/wave, reg double-buffer ----
__global__ __launch_bounds__(256, 2) void patch_stage1(
    const float* __restrict__ fuse,
    const float* __restrict__ img1,
    const float* __restrict__ img2,
    const unsigned int* __restrict__ order,
    float* __restrict__ partials)
{
    const int lane = threadIdx.x & 63;
    const int wave = threadIdx.x >> 6;
    const int bid  = blockIdx.x;
    // bijective XCD-contiguous swizzle; block owns 32 consecutive sorted slots
    const int S = ((bid & 7) * (NBLK / 8) + (bid >> 3)) * 32;
    const int roff = (lane >> 2) * WD + (lane & 3) * 4;

    f4 buf[2][18];   // [ping-pong][c*6 + u*3 + {fuse,img1,img2}]

    // issue chunk j's 18 loads into buf[bsel] (j, bsel compile-time in unroll)
    #define ISSUE(j, bsel) do {                                               \
        const uint2 o = *(const uint2*)(order + S + (j) * 8 + wave * 2);      \
        const int wA = o.x & 511, hA = (o.x >> 9) & 511, bA = (int)(o.x >> 18);\
        const int wB = o.y & 511, hB = (o.y >> 9) & 511, bB = (int)(o.y >> 18);\
        const size_t baseA = ((size_t)(bA * CD) * HD + hA) * WD + wA + roff;  \
        const size_t baseB = ((size_t)(bB * CD) * HD + hB) * WD + wB + roff;  \
        _Pragma("unroll")                                                     \
        for (int c = 0; c < CD; ++c) {                                        \
            buf[bsel][c*6+0] = *(const f4*)(fuse + baseA + (size_t)c * PLANE);\
            buf[bsel][c*6+1] = *(const f4*)(img1 + baseA + (size_t)c * PLANE);\
            buf[bsel][c*6+2] = *(const f4*)(img2 + baseA + (size_t)c * PLANE);\
            buf[bsel][c*6+3] = *(const f4*)(fuse + baseB + (size_t)c * PLANE);\
            buf[bsel][c*6+4] = *(const f4*)(img1 + baseB + (size_t)c * PLANE);\
            buf[bsel][c*6+5] = *(const f4*)(img2 + baseB + (size_t)c * PLANE);\
        }                                                                     \
    } while (0)

    float accT = 0.f;
    const float inv = 1.f / 256.f;

    ISSUE(0, 0);
    #pragma unroll
    for (int j = 0; j < ITER; ++j) {
        if (j < ITER - 1) ISSUE(j + 1, (j + 1) & 1);

        // ---- compute chunk j from buf[j&1] ----
        {
            float s1[2][3], q1[2][3], s2[2][3], q2[2][3];
            #pragma unroll
            for (int u = 0; u < 2; ++u) {
                #pragma unroll
                for (int c = 0; c < CD; ++c) {
                    const f4 a  = buf[j & 1][c*6 + u*3 + 1];
                    const f4 bb = buf[j & 1][c*6 + u*3 + 2];
                    s1[u][c] = a.x + a.y + a.z + a.w;
                    q1[u][c] = a.x*a.x + a.y*a.y + a.z*a.z + a.w*a.w;
                    s2[u][c] = bb.x + bb.y + bb.z + bb.w;
                    q2[u][c] = bb.x*bb.x + bb.y*bb.y + bb.z*bb.z + bb.w*bb.w;
                }
            }
            #pragma unroll
            for (int u = 0; u < 2; ++u) {
                #pragma unroll
                for (int c = 0; c < CD; ++c) {
                    s1[u][c] = wave_sum64(s1[u][c]);
                    q1[u][c] = wave_sum64(q1[u][c]);
                    s2[u][c] = wave_sum64(s2[u][c]);
                    q2[u][c] = wave_sum64(q2[u][c]);
                }
            }
            #pragma unroll
            for (int u = 0; u < 2; ++u) {
                #pragma unroll
                for (int c = 0; c < CD; ++c) {
                    const float mu1 = s1[u][c] * inv;
                    const float mu2 = s2[u][c] * inv;
                    const float sd1 = sqrtf(fmaxf(q1[u][c] * inv - mu1 * mu1, 0.f));
                    const float sd2 = sqrtf(fmaxf(q2[u][c] * inv - mu2 * mu2, 0.f));
                    const float den = sd1 + sd2 + 1e-6f;
                    const float w1 = sd1 / den;
                    const float w2 = sd2 / den;
                    const f4 vf = buf[j & 1][c*6 + u*3 + 0];
                    const f4 a  = buf[j & 1][c*6 + u*3 + 1];
                    const f4 bb = buf[j & 1][c*6 + u*3 + 2];
                    const f4 d0 = vf - (w1 * a + w2 * bb);
                    accT += (fabsf(d0.x) + fabsf(d0.y)) + (fabsf(d0.z) + fabsf(d0.w));
                }
            }
        }
    }
    #undef ISSUE

    accT = wave_sum64(accT);

    __shared__ float partsm[4];
    if (lane == 0) partsm[wave] = accT;
    __syncthreads();
    if (threadIdx.x == 0)
        partials[bid] = partsm[0] + partsm[1] + partsm[2] + partsm[3];
}

// ---- kernel 3: final reduction over 512 partials ----
__global__ __launch_bounds__(256) void patch_stage2(
    const float* __restrict__ partials, float* __restrict__ out)
{
    float s = 0.f;
    for (int i = threadIdx.x; i < NBLK; i += 256)
        s += partials[i];

    s = wave_sum64(s);

    __shared__ float partsm[4];
    const int lane = threadIdx.x & 63;
    const int wave = threadIdx.x >> 6;
    if (lane == 0) partsm[wave] = s;
    __syncthreads();
    if (threadIdx.x == 0)
        out[0] = (partsm[0] + partsm[1] + partsm[2] + partsm[3]) * (float)(1.0 / TOTAL_ELEMS);
}

extern "C" void kernel_launch(void* const* d_in, const int* in_sizes, int n_in,
                              void* d_out, int out_size, void* d_ws, size_t ws_size,
                              hipStream_t stream) {
    const float* fuse   = (const float*)d_in[0];
    const float* img1   = (const float*)d_in[1];
    const float* img2   = (const float*)d_in[2];
    const int*   coords = (const int*)d_in[3];
    float* out = (float*)d_out;

    unsigned int* order    = (unsigned int*)d_ws;            // 64 KB
    float*        partials = (float*)((char*)d_ws + NP * 4); // 2 KB

    build_order<<<BD, 256, 0, stream>>>(coords, order);
    patch_stage1<<<NBLK, 256, 0, stream>>>(fuse, img1, img2, order, partials);
    patch_stage2<<<1, 256, 0, stream>>>(partials, out);
}